// Round 6
// baseline (274.649 us; speedup 1.0000x reference)
//
#include <hip/hip_runtime.h>

// Sparse 2:4 grouped conv, MI355X.  R6: back to 16x16x32 MFMA with R2's
// proven 0-conflict LDS swizzle; double-buffered at BK=32 so LDS stays 32 KB
// (no R4 occupancy cliff) while each barrier drain is covered by 16 MFMA.

#define INF   1152
#define HO    56
#define LOUT  3136      // 56*56
#define XP    58        // padded spatial

typedef __attribute__((ext_vector_type(8))) short bf16x8;
typedef __attribute__((ext_vector_type(4))) float f32x4;

__device__ __forceinline__ unsigned short f2bf(float f) {
  union { float f; unsigned u; } v; v.f = f;
  unsigned r = v.u + 0x7fffu + ((v.u >> 16) & 1u);   // RNE
  return (unsigned short)(r >> 16);
}

__device__ __forceinline__ void async_load16(const void* g, void* l) {
  __builtin_amdgcn_global_load_lds(
      (const __attribute__((address_space(1))) void*)g,
      (__attribute__((address_space(3))) void*)l, 16, 0, 0);
}

// ---------------- fused prep: pad+transpose+cast x  |  gumbel+mask+pack W ------
__global__ __launch_bounds__(256) void prep_kernel(
    const float* __restrict__ x, const float* __restrict__ Ws,
    const float* __restrict__ cw, const float* __restrict__ gb,
    const float* __restrict__ pat,
    unsigned short* __restrict__ Xt, unsigned short* __restrict__ Wt) {
  __shared__ float lds[56 * 129];
  const int t   = threadIdx.x;
  const int bid = blockIdx.x;

  if (bid >= 3712) {                                 // ---- weight pack ----
    int idx = (bid - 3712) * 256 + t;                // 294912 total
    int c   = idx & 127;
    int of  = (idx >> 7) & 127;
    int gt  = idx >> 14;                             // g*9+tap
    int g   = gt / 9;
    int tap = gt - g * 9;
    int e   = ((g << 7) + of) * INF + c * 9 + tap;
    int q   = e >> 2, pos = e & 3;
    const float* cq = cw + q * 6;
    const float* gq = gb + q * 6;
    float best = cq[0] + gq[0]; int bi = 0;
    #pragma unroll
    for (int j = 1; j < 6; ++j) {
      float v2 = cq[j] + gq[j];
      if (v2 > best) { best = v2; bi = j; }          // strict > = first-max
    }
    Wt[idx] = f2bf(Ws[e] * pat[bi * 4 + pos]);
    return;
  }

  // ---- xpose: x (B,256,56,56) f32 -> Xt[bg][58][58][c=128] bf16, zero borders
  const int bg  = bid / 58;
  const int ihp = bid - bg * 58;
  uint4* dst = (uint4*)(Xt + ((bg * XP + ihp) * XP) * 128);
  if (ihp == 0 || ihp == XP - 1) {
    const uint4 z = {0u, 0u, 0u, 0u};
    for (int i = t; i < XP * 16; i += 256) dst[i] = z;
    return;
  }
  const int ih = ihp - 1;
  const float4* src = (const float4*)(x + (bg * 128) * LOUT + ih * HO);
  for (int i = t; i < 128 * 14; i += 256) {
    int c = i / 14, seg = i - c * 14;                // iw = seg*4
    float4 v = src[c * (LOUT / 4) + seg];
    float* row = &lds[(seg * 4) * 129 + c];
    row[0]       = v.x;
    row[129]     = v.y;
    row[2 * 129] = v.z;
    row[3 * 129] = v.w;
  }
  __syncthreads();
  for (int i = t; i < XP * 16; i += 256) {
    int iwp = i >> 4, oct = i & 15;
    uint4 val = {0u, 0u, 0u, 0u};
    if (iwp != 0 && iwp != XP - 1) {
      const float* s = &lds[(iwp - 1) * 129 + (oct << 3)];
      val.x = (unsigned)f2bf(s[0]) | ((unsigned)f2bf(s[1]) << 16);
      val.y = (unsigned)f2bf(s[2]) | ((unsigned)f2bf(s[3]) << 16);
      val.z = (unsigned)f2bf(s[4]) | ((unsigned)f2bf(s[5]) << 16);
      val.w = (unsigned)f2bf(s[6]) | ((unsigned)f2bf(s[7]) << 16);
    }
    dst[i] = val;
  }
}

// per-step global offsets: 36 steps = 9 taps x 4 kc chunks of 32 c
__device__ __forceinline__ void step_offs(int s, int g, int& aOff, int& bOff) {
  const int tap = s >> 2, kc = s & 3;
  const int th = tap / 3, tw = tap - th * 3;
  aOff = ((g * 9 + tap) << 14) + (kc << 5);
  bOff = ((th * XP + tw) << 7) + (kc << 5);
}

// ---------------- conv: implicit-GEMM, BK=32 double-buffer, 32 KB LDS --------
// R2's proven swizzle: logical chunk ch of row r at phys slot ch^((r>>1)&3).
// Staging: lane l -> row t>>2 (+64 pass), phys slot t&3, logical (t&3)^((t>>3)&3).
__global__ __launch_bounds__(256, 4) void conv_mfma_kernel(
    const unsigned short* __restrict__ Wt, const unsigned short* __restrict__ Xt,
    float* __restrict__ out) {
  __shared__ __align__(16) unsigned short sA[2][128 * 32];   // 2 x 8 KB
  __shared__ __align__(16) unsigned short sB[2][128 * 32];   // 2 x 8 KB
  const int t  = threadIdx.x;
  const int ln = t & 63, wv = t >> 6;
  const int wm = wv >> 1, wn = wv & 1;
  const int col = ln & 15, kq = ln >> 4;

  // XCD-aware swizzle: contiguous bg range per XCD for L2 locality
  const int lid   = blockIdx.y * 25 + blockIdx.x;
  const int v     = (lid & 7) * 200 + (lid >> 3);
  const int bg    = v / 25;
  const int tileN = v - bg * 25;
  const int g     = bg & 1;
  const int l0    = tileN << 7;

  // staging geometry (R2 verbatim)
  const int kqs  = (t & 3) ^ ((t >> 3) & 3);
  const int c8   = kqs << 3;
  const int aoff = ((t >> 2) << 7) + c8;           // of*128 + c
  int boff[2];
  #pragma unroll
  for (int p = 0; p < 2; ++p) {
    int ll = l0 + (p << 6) + (t >> 2);
    if (ll > LOUT - 1) ll = LOUT - 1;              // tail tile: clamp
    int oh = ll / HO, ow = ll - oh * HO;
    boff[p] = ((bg * XP + oh) * XP + ow) * 128 + c8;
  }
  const int ldsw = (wv << 9);                      // wave slice within pass
  const int swk  = (kq ^ ((col >> 1) & 3)) << 3;   // read-side phys chunk

  f32x4 acc[4][4];
  #pragma unroll
  for (int i = 0; i < 4; ++i)
    #pragma unroll
    for (int j = 0; j < 4; ++j) acc[i][j] = (f32x4){0.f, 0.f, 0.f, 0.f};

  // prologue: stage step 0 into buf 0
  {
    int aOff, bOff;
    step_offs(0, g, aOff, bOff);
    #pragma unroll
    for (int p = 0; p < 2; ++p) {
      async_load16(Wt + aOff + (p << 13) + aoff, &sA[0][(p << 11) + ldsw]);
      async_load16(Xt + bOff + boff[p],          &sB[0][(p << 11) + ldsw]);
    }
  }
  __syncthreads();

  #pragma unroll 2
  for (int s = 0; s < 36; ++s) {
    const int buf = s & 1;
    if (s < 35) {                                   // issue next step -> buf^1
      int aOff, bOff;
      step_offs(s + 1, g, aOff, bOff);
      #pragma unroll
      for (int p = 0; p < 2; ++p) {
        async_load16(Wt + aOff + (p << 13) + aoff, &sA[buf ^ 1][(p << 11) + ldsw]);
        async_load16(Xt + bOff + boff[p],          &sB[buf ^ 1][(p << 11) + ldsw]);
      }
    }
    // compute current step from buf — covers the drain of the s+1 loads
    bf16x8 af[4], bfr[4];
    #pragma unroll
    for (int mi = 0; mi < 4; ++mi)
      af[mi] = *(const bf16x8*)&sA[buf][(wm << 11) + (((mi << 4) + col) << 5) + swk];
    #pragma unroll
    for (int ni = 0; ni < 4; ++ni)
      bfr[ni] = *(const bf16x8*)&sB[buf][(wn << 11) + (((ni << 4) + col) << 5) + swk];
    #pragma unroll
    for (int mi = 0; mi < 4; ++mi)
      #pragma unroll
      for (int ni = 0; ni < 4; ++ni)
        acc[mi][ni] = __builtin_amdgcn_mfma_f32_16x16x32_bf16(
            af[mi], bfr[ni], acc[mi][ni], 0, 0, 0);
    __syncthreads();                                // protects buf overwrite @s+1
  }

  // epilogue: C/D layout col=lane&15, row=(lane>>4)*4+reg
  const int rowq = kq << 2;
  #pragma unroll
  for (int mi = 0; mi < 4; ++mi) {
    #pragma unroll
    for (int ni = 0; ni < 4; ++ni) {
      const int l = l0 + (wn << 6) + (ni << 4) + col;
      if (l < LOUT) {
        #pragma unroll
        for (int r = 0; r < 4; ++r) {
          const int of = (wm << 6) + (mi << 4) + rowq + r;
          out[(bg * 128 + of) * LOUT + l] = acc[mi][ni][r];
        }
      }
    }
  }
}

extern "C" void kernel_launch(void* const* d_in, const int* in_sizes, int n_in,
                              void* d_out, int out_size, void* d_ws, size_t ws_size,
                              hipStream_t stream) {
  const float* x   = (const float*)d_in[0];
  const float* Ws  = (const float*)d_in[1];
  const float* cw  = (const float*)d_in[2];
  const float* gb  = (const float*)d_in[3];
  const float* pat = (const float*)d_in[4];
  float* out = (float*)d_out;

  unsigned short* Wt = (unsigned short*)d_ws;                       // 576 KB
  unsigned short* Xt = (unsigned short*)((char*)d_ws + (1 << 20));  // 52.6 MB

  prep_kernel<<<4864, 256, 0, stream>>>(x, Ws, cw, gb, pat, Xt, Wt);
  conv_mfma_kernel<<<dim3(25, 64), 256, 0, stream>>>(Wt, Xt, out);
}